// Round 1
// baseline (243.092 us; speedup 1.0000x reference)
//
#include <hip/hip_runtime.h>
#include <stdint.h>

#define BDIM 4
#define LDIM 128
#define DDIM 256
#define CDIM 512
#define EPSLN 1e-5f

typedef float f32x4 __attribute__((ext_vector_type(4)));
typedef short s16x8 __attribute__((ext_vector_type(8)));

__device__ __forceinline__ unsigned short f2bf(float f) {
    unsigned u = __builtin_bit_cast(unsigned, f);
    u += 0x7fffu + ((u >> 16) & 1u);   // round-to-nearest-even (no NaNs in this data)
    return (unsigned short)(u >> 16);
}
__device__ __forceinline__ float bf2f(unsigned short h) {
    unsigned u = ((unsigned)h) << 16;
    return __builtin_bit_cast(float, u);
}

// ---------------------------------------------------------------------------
// Transpose + cast: src [B][L][D] f32  ->  dst32 [B][D][L] f32, dst16 same bf16
// grid (D/32, L/32, B), block 256
// ---------------------------------------------------------------------------
__global__ __launch_bounds__(256) void k_transpose(const float* __restrict__ src,
                                                   float* __restrict__ dst32,
                                                   unsigned short* __restrict__ dst16) {
    __shared__ float tile[32][33];
    const int d0 = blockIdx.x * 32, k0 = blockIdx.y * 32, b = blockIdx.z;
    const int tx = threadIdx.x & 31, ty = threadIdx.x >> 5;
#pragma unroll
    for (int jj = 0; jj < 4; ++jj) {
        int r = ty + jj * 8;
        tile[r][tx] = src[((size_t)(b * LDIM + k0 + r)) * DDIM + d0 + tx];
    }
    __syncthreads();
#pragma unroll
    for (int jj = 0; jj < 4; ++jj) {
        int r = ty + jj * 8;                 // local d
        float v = tile[tx][r];               // src[k0+tx][d0+r]
        size_t o = ((size_t)(b * DDIM + d0 + r)) * LDIM + k0 + tx;
        dst32[o] = v;
        dst16[o] = f2bf(v);
    }
}

// ---------------------------------------------------------------------------
// Gram matrices (fp32): which 0: QV=Q.V^T  1: VV  2: QQ  3: VQ=V.Q^T
// Reads the TRANSPOSED fp32 copies so lanes load contiguous float4s.
// grid (4 i-tiles, 4 which, B), block 256. Each thread: 4x4 register tile.
// ---------------------------------------------------------------------------
__global__ __launch_bounds__(256) void k_gram(const float* __restrict__ Qt,
                                              const float* __restrict__ Vt,
                                              float* __restrict__ grams) {
    const int it = blockIdx.x, which = blockIdx.y, b = blockIdx.z;
    const float* Xt;
    const float* Yt;
    if (which == 0)      { Xt = Qt; Yt = Vt; }
    else if (which == 1) { Xt = Vt; Yt = Vt; }
    else if (which == 2) { Xt = Qt; Yt = Qt; }
    else                 { Xt = Vt; Yt = Qt; }
    float* Cg = grams + (size_t)which * (BDIM * LDIM * LDIM) + (size_t)b * (LDIM * LDIM);

    const int i0 = it * 32 + ((threadIdx.x >> 5) << 2);  // 4 i rows
    const int kt = (threadIdx.x & 31) << 2;              // 4 k cols
    const float* xb = Xt + (size_t)b * DDIM * LDIM + i0;
    const float* yb = Yt + (size_t)b * DDIM * LDIM + kt;

    float acc[4][4] = {};
#pragma unroll 8
    for (int c = 0; c < DDIM; ++c) {
        f32x4 xv = *(const f32x4*)(xb + (size_t)c * LDIM);
        f32x4 yv = *(const f32x4*)(yb + (size_t)c * LDIM);
#pragma unroll
        for (int ii = 0; ii < 4; ++ii)
#pragma unroll
            for (int kk = 0; kk < 4; ++kk)
                acc[ii][kk] += xv[ii] * yv[kk];
    }
#pragma unroll
    for (int ii = 0; ii < 4; ++ii) {
        f32x4 r;
        r[0] = acc[ii][0]; r[1] = acc[ii][1]; r[2] = acc[ii][2]; r[3] = acc[ii][3];
        *(f32x4*)(Cg + (size_t)(i0 + ii) * LDIM + kt) = r;
    }
}

// ---------------------------------------------------------------------------
// E matrices: E = exp(0.5*gram - rowmax_over_unmasked), 0 at masked keys.
// ty 0:QV->E1  1:VV->E2  2:QQ->E1q  3:VQ->E2q
// grid (L, 4, B), block 128 (2 waves)
// ---------------------------------------------------------------------------
__global__ __launch_bounds__(128) void k_ebuild(const float* __restrict__ grams,
                                                float* __restrict__ Es,
                                                const int* __restrict__ mask) {
    const int row = blockIdx.x, ty = blockIdx.y, b = blockIdx.z;
    const int t = threadIdx.x;
    const size_t off = (size_t)ty * (BDIM * LDIM * LDIM) + ((size_t)(b * LDIM + row)) * LDIM;
    const float* src = grams + off;
    float* dst = Es + off;

    float lg = 0.5f * src[t];
    const bool valid = mask[b * LDIM + t] != 0;
    float lv = valid ? lg : -3.0e38f;
#pragma unroll
    for (int o = 32; o >= 1; o >>= 1) lv = fmaxf(lv, __shfl_xor(lv, o, 64));
    __shared__ float mx[2];
    if ((t & 63) == 0) mx[t >> 6] = lv;
    __syncthreads();
    float m = fmaxf(mx[0], mx[1]);
    dst[t] = valid ? __expf(lg - m) : 0.0f;
}

// ---------------------------------------------------------------------------
// Main fused kernel.
// grid (4 i-tiles, L j, B), block 256 (4 waves).
// Wave w: path = w>>1 (0: attn@V cols 0..255, 1: attn_q@Q cols 256..511),
//         nh = w&1 (which 128-col half of that path).
// MFMA 16x16x32 bf16: A[m=lane&15][k=quad*8+u], B[k=quad*8+u][n=lane&15],
//                     C row = quad*4+reg, col = lane&15.
// ---------------------------------------------------------------------------
__global__ __launch_bounds__(256) void k_main(const float* __restrict__ E1,
                                              const unsigned short* __restrict__ Vt16,
                                              const unsigned short* __restrict__ Qt16,
                                              const int* __restrict__ mask,
                                              const float* __restrict__ nw,
                                              const float* __restrict__ nb,
                                              float* __restrict__ out) {
    __shared__ unsigned short Vt_s[256][40];   // V^T K-chunk: row=d, col=k (pad->2-way free)
    __shared__ unsigned short Qt_s[256][40];
    __shared__ unsigned short P_s[32][136];    // bf16 P  (row=i-local, col=k), pad 8
    __shared__ unsigned short Pq_s[32][136];
    __shared__ float wln[512], bln[512];
    __shared__ float zinv_s[64];               // [path*32+row]
    __shared__ float rsum[32], rsum2[32], maskv[32];

    const int tid = threadIdx.x;
    const int i0 = blockIdx.x * 32;
    const int j = blockIdx.y;
    const int b = blockIdx.z;

    const int lane = tid & 63;
    const int q = lane >> 4;
    const int l15 = lane & 15;
    const int wv = tid >> 6;
    const int path = wv >> 1;
    const int nh = wv & 1;

    const int NE = BDIM * LDIM * LDIM;
    const float* E2 = E1 + NE;
    const float* E1q = E1 + 2 * NE;
    const float* E2q = E1 + 3 * NE;

    // phase 1: constants
    wln[tid] = nw[tid]; wln[tid + 256] = nw[tid + 256];
    bln[tid] = nb[tid]; bln[tid + 256] = nb[tid + 256];
    if (tid < 32) {
        rsum[tid] = 0.f; rsum2[tid] = 0.f;
        maskv[tid] = (mask[b * LDIM + i0 + tid] != 0) ? 1.0f : 0.0f;
    }

    // phase 2: build P = E1 (.) E2[j], Pq = E1q (.) E2q[j]  (bf16 into LDS)
    {
        const int m = tid >> 3;
        const int k0 = (tid & 7) * 16;
        const float* e1 = E1 + ((size_t)(b * LDIM + i0 + m)) * LDIM + k0;
        const float* e2 = E2 + ((size_t)(b * LDIM + j)) * LDIM + k0;
        const float* e1q = E1q + ((size_t)(b * LDIM + i0 + m)) * LDIM + k0;
        const float* e2q = E2q + ((size_t)(b * LDIM + j)) * LDIM + k0;
        union { unsigned short u[16]; s16x8 v[2]; } tp, tq;
#pragma unroll
        for (int u4 = 0; u4 < 16; u4 += 4) {
            f32x4 a = *(const f32x4*)(e1 + u4);
            f32x4 c = *(const f32x4*)(e2 + u4);
            f32x4 aq = *(const f32x4*)(e1q + u4);
            f32x4 cq = *(const f32x4*)(e2q + u4);
#pragma unroll
            for (int u = 0; u < 4; ++u) {
                tp.u[u4 + u] = f2bf(a[u] * c[u]);
                tq.u[u4 + u] = f2bf(aq[u] * cq[u]);
            }
        }
        *(s16x8*)&P_s[m][k0] = tp.v[0];
        *(s16x8*)&P_s[m][k0 + 8] = tp.v[1];
        *(s16x8*)&Pq_s[m][k0] = tq.v[0];
        *(s16x8*)&Pq_s[m][k0 + 8] = tq.v[1];
    }
    __syncthreads();

    // phase 3: Z row sums from the (quantized) P, so normalization is consistent
    {
        const int r = tid >> 2;            // 0..63
        const int part = tid & 3;
        const int row = r & 31, pth = r >> 5;
        const unsigned short* ps = pth ? &Pq_s[row][0] : &P_s[row][0];
        float s = 0.f;
#pragma unroll
        for (int u = 0; u < 32; ++u) s += bf2f(ps[part * 32 + u]);
        s += __shfl_xor(s, 1, 64);
        s += __shfl_xor(s, 2, 64);
        if (part == 0) zinv_s[pth * 32 + row] = 1.0f / s;
    }

    f32x4 acc[2][8];
#pragma unroll
    for (int mt = 0; mt < 2; ++mt)
#pragma unroll
        for (int nt = 0; nt < 8; ++nt) acc[mt][nt] = (f32x4){0.f, 0.f, 0.f, 0.f};

    const unsigned short* vtg = Vt16 + (size_t)b * DDIM * LDIM;
    const unsigned short* qtg = Qt16 + (size_t)b * DDIM * LDIM;

    for (int kc = 0; kc < 4; ++kc) {
        // stage V^T and Q^T K-chunks (columns kc*32..+32 of all 256 d-rows)
#pragma unroll
        for (int p = 0; p < 4; ++p) {
            const int d = p * 64 + (tid >> 2);
            const int sub = tid & 3;
            const size_t off = (size_t)d * LDIM + kc * 32 + sub * 8;
            *(s16x8*)&Vt_s[d][sub * 8] = *(const s16x8*)(vtg + off);
            *(s16x8*)&Qt_s[d][sub * 8] = *(const s16x8*)(qtg + off);
        }
        __syncthreads();

        const unsigned short(*As)[136] = path ? Pq_s : P_s;
        const unsigned short(*Bs)[40] = path ? Qt_s : Vt_s;
        const s16x8 a0 = *(const s16x8*)&As[l15][kc * 32 + q * 8];
        const s16x8 a1 = *(const s16x8*)&As[16 + l15][kc * 32 + q * 8];
#pragma unroll
        for (int nt = 0; nt < 8; ++nt) {
            const s16x8 bf = *(const s16x8*)&Bs[nh * 128 + nt * 16 + l15][q * 8];
            acc[0][nt] = __builtin_amdgcn_mfma_f32_16x16x32_bf16(a0, bf, acc[0][nt], 0, 0, 0);
            acc[1][nt] = __builtin_amdgcn_mfma_f32_16x16x32_bf16(a1, bf, acc[1][nt], 0, 0, 0);
        }
        __syncthreads();
    }

    // epilogue: normalize by Z, LayerNorm over 512, affine, i-mask, store
#pragma unroll
    for (int mt = 0; mt < 2; ++mt) {
#pragma unroll
        for (int reg = 0; reg < 4; ++reg) {
            const int row = mt * 16 + q * 4 + reg;
            const float zv = zinv_s[path * 32 + row];
            float s1 = 0.f, s2 = 0.f;
#pragma unroll
            for (int nt = 0; nt < 8; ++nt) {
                float v = acc[mt][nt][reg] * zv;
                s1 += v;
                s2 += v * v;
            }
#pragma unroll
            for (int o = 1; o <= 8; o <<= 1) {
                s1 += __shfl_xor(s1, o, 64);
                s2 += __shfl_xor(s2, o, 64);
            }
            if (l15 == 0) {
                atomicAdd(&rsum[row], s1);
                atomicAdd(&rsum2[row], s2);
            }
        }
    }
    __syncthreads();
#pragma unroll
    for (int mt = 0; mt < 2; ++mt) {
#pragma unroll
        for (int reg = 0; reg < 4; ++reg) {
            const int row = mt * 16 + q * 4 + reg;
            const float zv = zinv_s[path * 32 + row];
            const float mean = rsum[row] * (1.0f / 512.0f);
            const float var = rsum2[row] * (1.0f / 512.0f) - mean * mean;
            const float rstd = rsqrtf(var + EPSLN);
            const float mf = maskv[row];
            float* orow = out + (((size_t)(b * LDIM + i0 + row)) * LDIM + j) * CDIM;
#pragma unroll
            for (int nt = 0; nt < 8; ++nt) {
                const int c = path * 256 + nh * 128 + nt * 16 + l15;
                const float v = acc[mt][nt][reg] * zv;
                orow[c] = ((v - mean) * rstd * wln[c] + bln[c]) * mf;
            }
        }
    }
}

// ---------------------------------------------------------------------------
extern "C" void kernel_launch(void* const* d_in, const int* in_sizes, int n_in,
                              void* d_out, int out_size, void* d_ws, size_t ws_size,
                              hipStream_t stream) {
    const float* query = (const float*)d_in[0];
    const float* value = (const float*)d_in[1];
    const int* mask = (const int*)d_in[2];
    const float* nw = (const float*)d_in[3];
    const float* nb = (const float*)d_in[4];
    float* out = (float*)d_out;

    char* ws = (char*)d_ws;
    const size_t NG = (size_t)BDIM * LDIM * LDIM;      // 65536 floats per gram / E
    const size_t NT = (size_t)BDIM * DDIM * LDIM;      // 131072 elems per transposed mat

    float* grams = (float*)ws;                                   // 4 x 256 KiB
    float* Es = (float*)(ws + 4 * NG * 4);                       // 4 x 256 KiB
    unsigned short* Vt16 = (unsigned short*)(ws + 8 * NG * 4);   // 256 KiB
    unsigned short* Qt16 = (unsigned short*)(ws + 8 * NG * 4 + NT * 2);
    float* Vt32 = (float*)(ws + 8 * NG * 4 + 2 * NT * 2);        // 512 KiB
    float* Qt32 = Vt32 + NT;                                     // 512 KiB
    // total ws use: 3,670,016 bytes

    k_transpose<<<dim3(8, 4, 4), 256, 0, stream>>>(value, Vt32, Vt16);
    k_transpose<<<dim3(8, 4, 4), 256, 0, stream>>>(query, Qt32, Qt16);
    k_gram<<<dim3(4, 4, 4), 256, 0, stream>>>(Qt32, Vt32, grams);
    k_ebuild<<<dim3(128, 4, 4), 128, 0, stream>>>(grams, Es, mask);
    k_main<<<dim3(4, 128, 4), 256, 0, stream>>>(Es, Vt16, Qt16, mask, nw, nb, out);
}